// Round 12
// baseline (648.269 us; speedup 1.0000x reference)
//
#include <hip/hip_runtime.h>
#include <hip/hip_bf16.h>
#include <hip/hip_cooperative_groups.h>

namespace cg = cooperative_groups;

// Problem constants (from reference)
#define NN      50000
#define EE      200000
#define IN_DIM  32
#define HID     64
#define HEADS   4
#define OUTD    32
#define TSTEPS  3

typedef unsigned short bf16_t;
typedef __attribute__((ext_vector_type(8))) short  short8;
typedef __attribute__((ext_vector_type(4))) float  floatx4;

__device__ __forceinline__ float b2f(bf16_t u) {
    union { unsigned int i; float f; } v; v.i = ((unsigned int)u) << 16; return v.f;
}
__device__ __forceinline__ bf16_t f2b(float f) {
    union { float f; unsigned int i; } v; v.f = f;
    unsigned int r = v.i + 0x7FFF + ((v.i >> 16) & 1);   // RNE
    return (bf16_t)(r >> 16);
}

#define H0_BLOCKS ((NN + 31) / 32)   // h0 section: 32 nodes/block

// ---------------------------------------------------------------- fused setup (+h0)
__global__ __launch_bounds__(256) void k_setup(
        const void* W_in, const void* b_in, const void* att, const void* bconv,
        const void* Wg, const void* bg,
        const void* Wl_raw, const void* Wr_raw, const void* bl_raw, const void* br_raw,
        const void* feat_raw,
        float* attf, float* bcf, float* Wgf, float* bgf,
        bf16_t* __restrict__ Wt, bf16_t* __restrict__ WtS, float* __restrict__ bb,
        int* __restrict__ deg, int* __restrict__ flag, int* __restrict__ mbuf,
        bf16_t* __restrict__ h0, bf16_t* __restrict__ h) {
    __shared__ int bad;
    __shared__ float Ws[IN_DIM * HID];
    __shared__ float bs[HID];
    int t = threadIdx.x, bid = blockIdx.x;
    if (t == 0) bad = 0;
    __syncthreads();
    {
        const bf16_t* p = (const bf16_t*)W_in;
        int mybad = 0;
        for (int i = t; i < IN_DIM * HID; i += 256) {
            float v = b2f(p[i]);
            if (v != v || fabsf(v) > 100.f) mybad = 1;
        }
        if (mybad) atomicOr(&bad, 1);
    }
    __syncthreads();
    int f = bad ? 0 : 1;
    if (bid == 0 && t == 0) *flag = f;

    if (bid < 256) {
        int i = bid * 256 + t;              // over 512*128
        int n = i >> 7, k = i & 127;
        const void* W = (n < 256) ? Wl_raw : Wr_raw;
        int nn = (n < 256) ? n : n - 256;
        float v = f ? b2f(((const bf16_t*)W)[k * 256 + nn])
                    : ((const float*)W)[k * 256 + nn];
        Wt[n * 128 + k] = f2b(v);
        if (k < 64) {
            float v2 = f ? b2f(((const bf16_t*)W)[(k + 64) * 256 + nn])
                         : ((const float*)W)[(k + 64) * 256 + nn];
            WtS[n * 64 + k] = f2b(v + v2);   // step-0 weights: x=[h0|h0]
        }
        if (k == 0) {
            const void* b = (n < 256) ? bl_raw : br_raw;
            bb[n] = f ? b2f(((const bf16_t*)b)[nn]) : ((const float*)b)[nn];
        }
    } else if (bid < 267) {
        int i = (bid - 256) * 256 + t;      // over 2592
        const void* src; float* dst; int off;
        if      (i < 256)  { src = att;   dst = attf; off = i; }
        else if (i < 512)  { src = bconv; dst = bcf;  off = i - 256; }
        else if (i < 2560) { src = Wg;    dst = Wgf;  off = i - 512; }
        else if (i < 2592) { src = bg;    dst = bgf;  off = i - 2560; }
        else return;
        dst[off] = f ? b2f(((const bf16_t*)src)[off]) : ((const float*)src)[off];
    } else if (bid < 463) {
        int i = (bid - 267) * 256 + t;
        if (i < NN) deg[i] = 0;
        if (bid == 267 && t < 16) mbuf[t] = 0;
    } else {
        // h0: stage W_in/b_in once, then 8 groups x 4 nodes = 32 nodes/block
        for (int i = t; i < IN_DIM * HID; i += 256)
            Ws[i] = f ? b2f(((const bf16_t*)W_in)[i]) : ((const float*)W_in)[i];
        if (t < HID)
            bs[t] = f ? b2f(((const bf16_t*)b_in)[t]) : ((const float*)b_in)[t];
        __syncthreads();
        int nb = bid - 463;
        int wid = t >> 6, c = t & 63;
#pragma unroll
        for (int g = 0; g < 8; g++) {
            int node = (nb * 8 + g) * 4 + wid;
            if (node >= NN) break;
            float acc = bs[c];
            if (f) {
                const bf16_t* fr = (const bf16_t*)feat_raw + (size_t)node * IN_DIM;
#pragma unroll
                for (int k = 0; k < IN_DIM; k++) acc += b2f(fr[k]) * Ws[k * HID + c];
            } else {
                const float* fr = (const float*)feat_raw + (size_t)node * IN_DIM;
#pragma unroll
                for (int k = 0; k < IN_DIM; k++) acc += fr[k] * Ws[k * HID + c];
            }
            bf16_t o = f2b(acc);
            h0[(size_t)node * HID + c] = o;
            h [(size_t)node * HID + c] = o;
        }
    }
}

// ---------------------------------------------------------------- hist: edge degree + mask buckets
__global__ __launch_bounds__(256) void k_hist_all(const int* __restrict__ dst,
                                                  const int* __restrict__ mask,
                                                  int* __restrict__ deg,
                                                  int* __restrict__ mbuf) {
    int t = threadIdx.x, bid = blockIdx.x;
    int i = bid * 256 + t;
    if (i < EE) atomicAdd(&deg[dst[i]], 1);
    if (bid < (NN + 255) / 256) {
        __shared__ int wcnt[4][4];
        int wid = t >> 6, lane = t & 63;
        int ni = bid * 256 + t;
        bool valid = ni < NN;
        int v = 0;
        if (valid) { int m = mask[ni]; v = m < 0 ? 0 : (m > 3 ? 3 : m); }
#pragma unroll
        for (int b = 0; b < 4; b++) {
            unsigned long long mm = __ballot(valid && v == b);
            if (lane == 0) wcnt[wid][b] = __popcll(mm);
        }
        __syncthreads();
        if (t < 4) {
            int s = wcnt[0][t] + wcnt[1][t] + wcnt[2][t] + wcnt[3][t];
            if (s) atomicAdd(&mbuf[t], s);
        }
    }
}

// ---------------------------------------------------------------- CSR scans
__global__ __launch_bounds__(256) void k_scan_partial(const int* __restrict__ deg,
                                                      int* __restrict__ part, int n) {
    __shared__ int sd[256];
    int t = threadIdx.x;
    int base = blockIdx.x * 1024;
    int s = 0;
#pragma unroll
    for (int j = 0; j < 4; j++) {
        int i = base + t * 4 + j;
        if (i < n) s += deg[i];
    }
    sd[t] = s; __syncthreads();
    for (int off = 128; off > 0; off >>= 1) {
        if (t < off) sd[t] += sd[t + off];
        __syncthreads();
    }
    if (t == 0) part[blockIdx.x] = sd[0];
}

// mbuf: [0..3] counts, [4..7] cursors (bucket v at mbuf[4+v]), [8..10] active/step
__global__ __launch_bounds__(256) void k_scan_final(const int* __restrict__ deg,
                                                    const int* __restrict__ part,
                                                    int* __restrict__ row_ptr,
                                                    int* __restrict__ cursor,
                                                    int n, int nch,
                                                    int* __restrict__ mbuf) {
    __shared__ int sc[256];
    __shared__ int bpref;
    int t = threadIdx.x;
    int bid = blockIdx.x;
    if (t == 0) {
        int acc = 0;
        for (int i = 0; i < bid; i++) acc += part[i];
        bpref = acc;
        if (bid == 0) {
            int tot = 0;
            for (int i = 0; i < nch; i++) tot += part[i];
            row_ptr[n] = tot;
            int c1 = mbuf[1], c2 = mbuf[2], c3 = mbuf[3];
            mbuf[7] = 0;              // bucket 3 cursor
            mbuf[6] = c3;             // bucket 2
            mbuf[5] = c3 + c2;        // bucket 1
            mbuf[4] = c3 + c2 + c1;   // bucket 0
            mbuf[8] = c3 + c2 + c1;   // active at step 0
            mbuf[9] = c3 + c2;        // step 1
            mbuf[10] = c3;            // step 2
        }
    }
    int base = bid * 1024;
    int v[4]; int s = 0;
#pragma unroll
    for (int j = 0; j < 4; j++) {
        int i = base + t * 4 + j;
        v[j] = (i < n) ? deg[i] : 0;
        s += v[j];
    }
    sc[t] = s; __syncthreads();
    for (int off = 1; off < 256; off <<= 1) {
        int add = (t >= off) ? sc[t - off] : 0;
        __syncthreads();
        sc[t] += add;
        __syncthreads();
    }
    int run = sc[t] - s + bpref;
#pragma unroll
    for (int j = 0; j < 4; j++) {
        int i = base + t * 4 + j;
        if (i < n) { row_ptr[i] = run; cursor[i] = run; run += v[j]; }
    }
}

// ---------------------------------------------------------------- scatter: CSR cols (mask-packed) + compaction order
__global__ __launch_bounds__(256) void k_scatter_all(const int* __restrict__ src,
                                                     const int* __restrict__ dst,
                                                     int* __restrict__ cursor,
                                                     int* __restrict__ col,
                                                     const int* __restrict__ mask,
                                                     int* __restrict__ mbuf,
                                                     int* __restrict__ order) {
    int t = threadIdx.x, bid = blockIdx.x;
    int i = bid * 256 + t;
    if (i < EE) {
        int sv = src[i];
        int m = mask[sv]; m = m < 0 ? 0 : (m > 3 ? 3 : m);
        int d = dst[i];
        int pos = atomicAdd(&cursor[d], 1);   // 50k distinct addrs: fine
        col[pos] = sv | (m << 28);
    }
    if (bid < (NN + 255) / 256) {
        __shared__ int wcnt[4][4];
        __shared__ int bbase[4];
        int wid = t >> 6, lane = t & 63;
        int ni = bid * 256 + t;
        bool valid = ni < NN;
        int v = 0;
        if (valid) { int m = mask[ni]; v = m < 0 ? 0 : (m > 3 ? 3 : m); }
        int rank = 0;
#pragma unroll
        for (int b = 0; b < 4; b++) {
            unsigned long long mm = __ballot(valid && v == b);
            if (valid && v == b)
                rank = __popcll(mm & ((lane == 0) ? 0ull : (~0ull >> (64 - lane))));
            if (lane == 0) wcnt[wid][b] = __popcll(mm);
        }
        __syncthreads();
        if (t < 4) {
            int tot = wcnt[0][t] + wcnt[1][t] + wcnt[2][t] + wcnt[3][t];
            bbase[t] = atomicAdd(&mbuf[4 + t], tot);   // one atomic/bucket/block
        }
        __syncthreads();
        if (valid) {
            int wpre = 0;
            for (int ww = 0; ww < wid; ww++) wpre += wcnt[ww][v];
            order[bbase[v] + wpre + rank] = ni;
        }
    }
}

// ================================================================ mega-kernel phases
// shared LDS buffer: 64*136 + 128*136 bf16 = 51 KB -> 3 blocks/CU

__device__ void dev_gemm64(const bf16_t* __restrict__ h0,
                           const bf16_t* __restrict__ WtS,
                           const float* __restrict__ bb,
                           bf16_t* __restrict__ xl, bf16_t* __restrict__ xr,
                           const int* __restrict__ order, int count,
                           bf16_t* smem) {
    bf16_t* As = smem;                 // 64*72
    bf16_t* Bs = smem + 64 * 72;       // 128*72
    bf16_t* Cs = smem;                 // 64*136
    int t = threadIdx.x;
    int ntiles = ((count + 63) >> 6) * 4;
    for (int tile = blockIdx.x; tile < ntiles; tile += gridDim.x) {
        int mbase = (tile >> 2) * 64;
        int yt = tile & 3;
        int nbase = yt * 128;
        {
            int ln = t >> 2, lq = t & 3;
            int idx = mbase + ln;
            int node = (idx < count) ? order[idx] : -1;
            ulonglong2 z; z.x = 0; z.y = 0;
            ulonglong2 v0 = z, v1 = z;
            if (node >= 0) {
                v0 = *(const ulonglong2*)(h0 + (size_t)node * HID + lq * 16);
                v1 = *(const ulonglong2*)(h0 + (size_t)node * HID + lq * 16 + 8);
            }
            *(ulonglong2*)(&As[ln * 72 + lq * 16]) = v0;
            *(ulonglong2*)(&As[ln * 72 + lq * 16 + 8]) = v1;
        }
        {
            int n = t >> 1, kc = (t & 1) * 32;
            const bf16_t* srcp = WtS + (size_t)(nbase + n) * 64 + kc;
            bf16_t* dstp = &Bs[n * 72 + kc];
            *(ulonglong2*)(dstp)      = *(const ulonglong2*)(srcp);
            *(ulonglong2*)(dstp + 8)  = *(const ulonglong2*)(srcp + 8);
            *(ulonglong2*)(dstp + 16) = *(const ulonglong2*)(srcp + 16);
            *(ulonglong2*)(dstp + 24) = *(const ulonglong2*)(srcp + 24);
        }
        __syncthreads();

        int wv = t >> 6, lane = t & 63, mrow = lane & 15, quad = lane >> 4;
        floatx4 acc[8];
#pragma unroll
        for (int nf = 0; nf < 8; nf++) acc[nf] = (floatx4){0.f, 0.f, 0.f, 0.f};
#pragma unroll
        for (int kq = 0; kq < 2; kq++) {
            short8 a = *(const short8*)(&As[(wv * 16 + mrow) * 72 + kq * 32 + quad * 8]);
#pragma unroll
            for (int nf = 0; nf < 8; nf++) {
                short8 b = *(const short8*)(&Bs[(nf * 16 + mrow) * 72 + kq * 32 + quad * 8]);
                acc[nf] = __builtin_amdgcn_mfma_f32_16x16x32_bf16(a, b, acc[nf], 0, 0, 0);
            }
        }
        __syncthreads();

#pragma unroll
        for (int nf = 0; nf < 8; nf++) {
            float bv = bb[nbase + nf * 16 + mrow];
#pragma unroll
            for (int r = 0; r < 4; r++) {
                int m = wv * 16 + quad * 4 + r;
                Cs[m * 136 + nf * 16 + mrow] = f2b(acc[nf][r] + bv);
            }
        }
        __syncthreads();

        bf16_t* outp = (yt < 2) ? xl : xr;
        int cc = (yt & 1) * 128;
#pragma unroll
        for (int i = 0; i < 4; i++) {
            int c = t + i * 256;
            int m = c >> 4, kc = (c & 15) * 8;
            int idx = mbase + m;
            if (idx < count) {
                int node = order[idx];
                *(ulonglong2*)(outp + (size_t)node * 256 + cc + kc) =
                    *(const ulonglong2*)(&Cs[m * 136 + kc]);
            }
        }
        __syncthreads();   // Cs reads done before next tile's staging
    }
}

__device__ void dev_gemm128(const bf16_t* __restrict__ h,
                            const bf16_t* __restrict__ h0,
                            const bf16_t* __restrict__ Wt,
                            const float* __restrict__ bb,
                            bf16_t* __restrict__ xl, bf16_t* __restrict__ xr,
                            const int* __restrict__ order, int count,
                            bf16_t* smem) {
    bf16_t* As = smem;                 // 64*136
    bf16_t* Bs = smem + 64 * 136;      // 128*136
    bf16_t* Cs = smem;
    int t = threadIdx.x;
    int ntiles = ((count + 63) >> 6) * 4;
    for (int tile = blockIdx.x; tile < ntiles; tile += gridDim.x) {
        int mbase = (tile >> 2) * 64;
        int yt = tile & 3;
        int nbase = yt * 128;
        {
            int ln = t >> 2, lq = t & 3;
            int idx = mbase + ln;
            int node = (idx < count) ? order[idx] : -1;
            ulonglong2 z; z.x = 0; z.y = 0;
#pragma unroll
            for (int j = 0; j < 2; j++) {
                int chunk = lq + j * 4;
                ulonglong2 vh = z, vh0 = z;
                if (node >= 0) {
                    vh  = *(const ulonglong2*)(h  + (size_t)node * HID + chunk * 8);
                    vh0 = *(const ulonglong2*)(h0 + (size_t)node * HID + chunk * 8);
                }
                *(ulonglong2*)(&As[ln * 136 + chunk * 8]) = vh;
                *(ulonglong2*)(&As[ln * 136 + 64 + chunk * 8]) = vh0;
            }
        }
#pragma unroll
        for (int i = 0; i < 8; i++) {
            int c = t + i * 256;
            int n = c >> 4, kc = (c & 15) * 8;
            *(ulonglong2*)(&Bs[n * 136 + kc]) =
                *(const ulonglong2*)(Wt + (size_t)(nbase + n) * 128 + kc);
        }
        __syncthreads();

        int wv = t >> 6, lane = t & 63, mrow = lane & 15, quad = lane >> 4;
        floatx4 acc[8];
#pragma unroll
        for (int nf = 0; nf < 8; nf++) acc[nf] = (floatx4){0.f, 0.f, 0.f, 0.f};
#pragma unroll
        for (int kq = 0; kq < 4; kq++) {
            short8 a = *(const short8*)(&As[(wv * 16 + mrow) * 136 + kq * 32 + quad * 8]);
#pragma unroll
            for (int nf = 0; nf < 8; nf++) {
                short8 b = *(const short8*)(&Bs[(nf * 16 + mrow) * 136 + kq * 32 + quad * 8]);
                acc[nf] = __builtin_amdgcn_mfma_f32_16x16x32_bf16(a, b, acc[nf], 0, 0, 0);
            }
        }
        __syncthreads();

#pragma unroll
        for (int nf = 0; nf < 8; nf++) {
            float bv = bb[nbase + nf * 16 + mrow];
#pragma unroll
            for (int r = 0; r < 4; r++) {
                int m = wv * 16 + quad * 4 + r;
                Cs[m * 136 + nf * 16 + mrow] = f2b(acc[nf][r] + bv);
            }
        }
        __syncthreads();

        bf16_t* outp = (yt < 2) ? xl : xr;
        int cc = (yt & 1) * 128;
#pragma unroll
        for (int i = 0; i < 4; i++) {
            int c = t + i * 256;
            int m = c >> 4, kc = (c & 15) * 8;
            int idx = mbase + m;
            if (idx < count) {
                int node = order[idx];
                *(ulonglong2*)(outp + (size_t)node * 256 + cc + kc) =
                    *(const ulonglong2*)(&Cs[m * 136 + kc]);
            }
        }
        __syncthreads();
    }
}

__device__ void dev_agg(bf16_t* __restrict__ h,
                        const bf16_t* __restrict__ xl,
                        const bf16_t* __restrict__ xr,
                        const float* __restrict__ att,
                        const float* __restrict__ b_conv,
                        const int* __restrict__ row_ptr,
                        const int* __restrict__ col,
                        const int* __restrict__ order, int count, int step) {
    int wid = threadIdx.x >> 6;
    int lane = threadIdx.x & 63;
    float4 attv = *(const float4*)(att + lane * 4);
    float4 bcv  = *(const float4*)(b_conv + lane * 4);

    for (int idx = blockIdx.x * 4 + wid; idx < count; idx += gridDim.x * 4) {
        int node = order[idx];

        ushort4 xru = *(const ushort4*)(xr + (size_t)node * 256 + lane * 4);
        float xr0 = b2f(xru.x), xr1 = b2f(xru.y), xr2 = b2f(xru.z), xr3 = b2f(xru.w);

        float a0 = 0.f, a1 = 0.f, a2 = 0.f, a3 = 0.f, l = 0.f;

        auto do_edge = [&](int s) {
            ushort4 xu = *(const ushort4*)(xl + (size_t)s * 256 + lane * 4);
            float x0 = b2f(xu.x), x1 = b2f(xu.y), x2 = b2f(xu.z), x3 = b2f(xu.w);
            float v0 = x0 + xr0; v0 = v0 > 0.f ? v0 : 0.2f * v0;
            float v1 = x1 + xr1; v1 = v1 > 0.f ? v1 : 0.2f * v1;
            float v2 = x2 + xr2; v2 = v2 > 0.f ? v2 : 0.2f * v2;
            float v3 = x3 + xr3; v3 = v3 > 0.f ? v3 : 0.2f * v3;
            float part = attv.x * v0 + attv.y * v1 + attv.z * v2 + attv.w * v3;
            part += __shfl_xor(part, 1, 64);
            part += __shfl_xor(part, 2, 64);
            part += __shfl_xor(part, 4, 64);
            part += __shfl_xor(part, 8, 64);
            float p = __expf(part);
            l += p;
            a0 += p * x0; a1 += p * x1; a2 += p * x2; a3 += p * x3;
        };

        do_edge(node);                                    // implicit self-loop
        int e0 = row_ptr[node], e1 = row_ptr[node + 1];
        int e = e0;
        for (; e + 3 < e1; e += 4) {
            int c0 = col[e], c1 = col[e + 1], c2 = col[e + 2], c3 = col[e + 3];
            if (((unsigned)c0 >> 28) > (unsigned)step) do_edge(c0 & 0x0FFFFFFF);
            if (((unsigned)c1 >> 28) > (unsigned)step) do_edge(c1 & 0x0FFFFFFF);
            if (((unsigned)c2 >> 28) > (unsigned)step) do_edge(c2 & 0x0FFFFFFF);
            if (((unsigned)c3 >> 28) > (unsigned)step) do_edge(c3 & 0x0FFFFFFF);
        }
        for (; e < e1; e++) {
            int c = col[e];
            if (((unsigned)c >> 28) > (unsigned)step) do_edge(c & 0x0FFFFFFF);
        }

        float inv = 1.f / l;                              // l>0 (self-loop alive)
        float t0 = a0 * inv + bcv.x;
        float t1 = a1 * inv + bcv.y;
        float t2 = a2 * inv + bcv.z;
        float t3 = a3 * inv + bcv.w;
        t0 += __shfl_xor(t0, 16, 64); t0 += __shfl_xor(t0, 32, 64);
        t1 += __shfl_xor(t1, 16, 64); t1 += __shfl_xor(t1, 32, 64);
        t2 += __shfl_xor(t2, 16, 64); t2 += __shfl_xor(t2, 32, 64);
        t3 += __shfl_xor(t3, 16, 64); t3 += __shfl_xor(t3, 32, 64);
        if (lane < 16) {
            ushort4 o;
            o.x = f2b(tanhf(t0)); o.y = f2b(tanhf(t1));
            o.z = f2b(tanhf(t2)); o.w = f2b(tanhf(t3));
            *(ushort4*)(h + (size_t)node * HID + lane * 4) = o;
        }
    }
}

__device__ void dev_out(const bf16_t* __restrict__ h,
                        const float* __restrict__ Wg,
                        const float* __restrict__ bg,
                        const int* __restrict__ cs,
                        void* __restrict__ out, int flagv, bf16_t* smem) {
    float* Ws = (float*)smem;             // 2048 floats
    float* bs = (float*)smem + 2048;      // 32 floats
    int t = threadIdx.x;
    for (int i = t; i < HID * OUTD; i += 256) Ws[i] = Wg[i];
    if (t < OUTD) bs[t] = bg[t];
    __syncthreads();
    int nb_tot = (NN + 7) / 8;
    for (int nb = blockIdx.x; nb < nb_tot; nb += gridDim.x) {
        int node = nb * 8 + (t >> 5);
        int c = t & 31;
        if (node < NN) {
            float res = 0.f;
            if (cs[node] > 0) {
                const bf16_t* hr = h + (size_t)node * HID;
                float acc = bs[c];
#pragma unroll
                for (int k = 0; k < HID; k++) acc += b2f(hr[k]) * Ws[k * OUTD + c];
                res = acc;
            }
            size_t idx = (size_t)node * OUTD + c;
            if (flagv) ((bf16_t*)out)[idx] = f2b(res);
            else       ((float*)out)[idx]  = res;
        }
    }
}

// ---------------------------------------------------------------- cooperative mega-kernel: 3x(gemm+agg) + out
__global__ __launch_bounds__(256) void k_mega(
        bf16_t* h, const bf16_t* h0, const bf16_t* Wt, const bf16_t* WtS,
        const float* bb, const float* attf, const float* bcf,
        const int* row_ptr, const int* colA, const int* order, const int* mbuf,
        const float* Wgf, const float* bgf, const int* cstate, void* out,
        const int* flag, bf16_t* xl, bf16_t* xr) {
    __shared__ bf16_t smem[64 * 136 + 128 * 136];   // 51 KB -> 3 blocks/CU
    cg::grid_group grid = cg::this_grid();

    dev_gemm64(h0, WtS, bb, xl, xr, order, mbuf[8], smem);
    grid.sync();
    dev_agg(h, xl, xr, attf, bcf, row_ptr, colA, order, mbuf[8], 0);
    grid.sync();
    dev_gemm128(h, h0, Wt, bb, xl, xr, order, mbuf[9], smem);
    grid.sync();
    dev_agg(h, xl, xr, attf, bcf, row_ptr, colA, order, mbuf[9], 1);
    grid.sync();
    dev_gemm128(h, h0, Wt, bb, xl, xr, order, mbuf[10], smem);
    grid.sync();
    dev_agg(h, xl, xr, attf, bcf, row_ptr, colA, order, mbuf[10], 2);
    grid.sync();
    dev_out(h, Wgf, bgf, cstate, out, *flag, smem);
}

// ---------------------------------------------------------------- host
static inline size_t alignup(size_t x) { return (x + 255) & ~(size_t)255; }

extern "C" void kernel_launch(void* const* d_in, const int* in_sizes, int n_in,
                              void* d_out, int out_size, void* d_ws, size_t ws_size,
                              hipStream_t stream) {
    const void* feat_raw  = d_in[0];
    const void* W_in_raw  = d_in[1];
    const void* b_in_raw  = d_in[2];
    const void* Wl_raw    = d_in[3];
    const void* bl_raw    = d_in[4];
    const void* Wr_raw    = d_in[5];
    const void* br_raw    = d_in[6];
    const void* att_raw   = d_in[7];
    const void* bconv_raw = d_in[8];
    const void* Wg_raw    = d_in[9];
    const void* bg_raw    = d_in[10];
    const int* edge       = (const int*)d_in[11];    // [2][EE]: src row, dst row
    const int* nmask      = (const int*)d_in[12];
    const int* cstate     = (const int*)d_in[13];

    const int* e_src = edge;
    const int* e_dst = edge + EE;

    const size_t SZ_HB   = alignup((size_t)NN * HID * sizeof(bf16_t));
    const size_t SZ_X    = alignup((size_t)NN * 256 * sizeof(bf16_t));
    const size_t SZ_I    = alignup((size_t)NN * sizeof(int));
    const size_t SZ_RP   = alignup((size_t)(NN + 1) * sizeof(int));
    const size_t SZ_COL  = alignup((size_t)EE * sizeof(int));
    const int nch = (NN + 1023) / 1024;
    const size_t SZ_PART = alignup((size_t)(nch + 1) * sizeof(int));
    const size_t SZ_WT   = alignup((size_t)512 * 128 * sizeof(bf16_t));
    const size_t SZ_WTS  = alignup((size_t)512 * 64 * sizeof(bf16_t));
    const size_t SZ_B    = alignup(512 * sizeof(float));
    const size_t SZ_WG   = alignup((size_t)HID * OUTD * sizeof(float));

    char* w = (char*)d_ws;
    bf16_t* h0   = (bf16_t*)w; w += SZ_HB;
    bf16_t* h    = (bf16_t*)w; w += SZ_HB;
    bf16_t* xl   = (bf16_t*)w; w += SZ_X;
    bf16_t* xr   = (bf16_t*)w; w += SZ_X;
    int* deg     = (int*)w;    w += SZ_I;
    int* row_ptr = (int*)w;    w += SZ_RP;
    int* cursor  = (int*)w;    w += SZ_I;
    int* colA    = (int*)w;    w += SZ_COL;
    int* order   = (int*)w;    w += SZ_I;
    int* part    = (int*)w;    w += SZ_PART;
    bf16_t* Wt   = (bf16_t*)w; w += SZ_WT;
    bf16_t* WtS  = (bf16_t*)w; w += SZ_WTS;
    float* bb    = (float*)w;  w += SZ_B;
    float* attf  = (float*)w;  w += SZ_B;
    float* bcf   = (float*)w;  w += SZ_B;
    float* Wgf   = (float*)w;  w += SZ_WG;
    float* bgf   = (float*)w;  w += SZ_B;
    int* flag    = (int*)w;    w += 256;
    int* mbuf    = (int*)w;    w += 256;
    if ((size_t)(w - (char*)d_ws) > ws_size) return;

    // ---- fused setup: flag + weights + deg/mbuf zero + h0
    k_setup<<<463 + H0_BLOCKS, 256, 0, stream>>>(
        W_in_raw, b_in_raw, att_raw, bconv_raw, Wg_raw, bg_raw,
        Wl_raw, Wr_raw, bl_raw, br_raw, feat_raw,
        attf, bcf, Wgf, bgf, Wt, WtS, bb, deg, flag, mbuf, h0, h);

    // ---- CSR + compaction
    k_hist_all<<<(EE + 255) / 256, 256, 0, stream>>>(e_dst, nmask, deg, mbuf);
    k_scan_partial<<<nch, 256, 0, stream>>>(deg, part, NN);
    k_scan_final<<<nch, 256, 0, stream>>>(deg, part, row_ptr, cursor, NN, nch, mbuf);
    k_scatter_all<<<(EE + 255) / 256, 256, 0, stream>>>(e_src, e_dst, cursor, colA,
                                                        nmask, mbuf, order);

    // ---- cooperative mega-kernel: gemm0, agg0, gemm1, agg1, gemm2, agg2, out
    int occ = 0;
    if (hipOccupancyMaxActiveBlocksPerMultiprocessor(&occ, k_mega, 256, 0) != hipSuccess
        || occ < 1) occ = 2;
    int ncu = 256;
    {
        int dev = 0;
        if (hipGetDevice(&dev) == hipSuccess) {
            int v = 0;
            if (hipDeviceGetAttribute(&v, hipDeviceAttributeMultiprocessorCount, dev)
                == hipSuccess && v > 0) ncu = v;
        }
    }
    dim3 grid(occ * ncu), block(256);
    void* out_p = d_out;
    void* kargs[] = {
        (void*)&h, (void*)&h0, (void*)&Wt, (void*)&WtS, (void*)&bb,
        (void*)&attf, (void*)&bcf, (void*)&row_ptr, (void*)&colA, (void*)&order,
        (void*)&mbuf, (void*)&Wgf, (void*)&bgf, (void*)&cstate, (void*)&out_p,
        (void*)&flag, (void*)&xl, (void*)&xr };
    hipLaunchCooperativeKernel((const void*)k_mega, grid, block, kargs, 0, stream);
}

// Round 13
// 250.547 us; speedup vs baseline: 2.5874x; 2.5874x over previous
//
#include <hip/hip_runtime.h>
#include <hip/hip_bf16.h>

// Problem constants (from reference)
#define NN      50000
#define EE      200000
#define IN_DIM  32
#define HID     64
#define HEADS   4
#define OUTD    32
#define TSTEPS  3

typedef unsigned short bf16_t;
typedef __attribute__((ext_vector_type(8))) short  short8;
typedef __attribute__((ext_vector_type(4))) float  floatx4;

__device__ __forceinline__ float b2f(bf16_t u) {
    union { unsigned int i; float f; } v; v.i = ((unsigned int)u) << 16; return v.f;
}
__device__ __forceinline__ bf16_t f2b(float f) {
    union { float f; unsigned int i; } v; v.f = f;
    unsigned int r = v.i + 0x7FFF + ((v.i >> 16) & 1);   // RNE
    return (bf16_t)(r >> 16);
}

#define H0_BLOCKS ((NN + 31) / 32)   // h0 section: 32 nodes/block

// ---------------------------------------------------------------- fused setup (+h0)
__global__ __launch_bounds__(256) void k_setup(
        const void* W_in, const void* b_in, const void* att, const void* bconv,
        const void* Wg, const void* bg,
        const void* Wl_raw, const void* Wr_raw, const void* bl_raw, const void* br_raw,
        const void* feat_raw,
        float* attf, float* bcf, float* Wgf, float* bgf,
        bf16_t* __restrict__ Wt, bf16_t* __restrict__ WtS, float* __restrict__ bb,
        int* __restrict__ deg, int* __restrict__ flag, int* __restrict__ mbuf,
        bf16_t* __restrict__ h0, bf16_t* __restrict__ h) {
    __shared__ int bad;
    __shared__ float Ws[IN_DIM * HID];
    __shared__ float bs[HID];
    int t = threadIdx.x, bid = blockIdx.x;
    if (t == 0) bad = 0;
    __syncthreads();
    {
        const bf16_t* p = (const bf16_t*)W_in;
        int mybad = 0;
        for (int i = t; i < IN_DIM * HID; i += 256) {
            float v = b2f(p[i]);
            if (v != v || fabsf(v) > 100.f) mybad = 1;
        }
        if (mybad) atomicOr(&bad, 1);
    }
    __syncthreads();
    int f = bad ? 0 : 1;
    if (bid == 0 && t == 0) *flag = f;

    if (bid < 256) {
        int i = bid * 256 + t;              // over 512*128
        int n = i >> 7, k = i & 127;
        const void* W = (n < 256) ? Wl_raw : Wr_raw;
        int nn = (n < 256) ? n : n - 256;
        float v = f ? b2f(((const bf16_t*)W)[k * 256 + nn])
                    : ((const float*)W)[k * 256 + nn];
        Wt[n * 128 + k] = f2b(v);
        if (k < 64) {
            float v2 = f ? b2f(((const bf16_t*)W)[(k + 64) * 256 + nn])
                         : ((const float*)W)[(k + 64) * 256 + nn];
            WtS[n * 64 + k] = f2b(v + v2);   // step-0 weights: x=[h0|h0]
        }
        if (k == 0) {
            const void* b = (n < 256) ? bl_raw : br_raw;
            bb[n] = f ? b2f(((const bf16_t*)b)[nn]) : ((const float*)b)[nn];
        }
    } else if (bid < 267) {
        int i = (bid - 256) * 256 + t;      // over 2592
        const void* src; float* dst; int off;
        if      (i < 256)  { src = att;   dst = attf; off = i; }
        else if (i < 512)  { src = bconv; dst = bcf;  off = i - 256; }
        else if (i < 2560) { src = Wg;    dst = Wgf;  off = i - 512; }
        else if (i < 2592) { src = bg;    dst = bgf;  off = i - 2560; }
        else return;
        dst[off] = f ? b2f(((const bf16_t*)src)[off]) : ((const float*)src)[off];
    } else if (bid < 463) {
        int i = (bid - 267) * 256 + t;
        if (i < NN) deg[i] = 0;
        if (bid == 267 && t < 16) mbuf[t] = 0;
    } else {
        // h0: stage W_in/b_in once, then 8 groups x 4 nodes = 32 nodes/block
        for (int i = t; i < IN_DIM * HID; i += 256)
            Ws[i] = f ? b2f(((const bf16_t*)W_in)[i]) : ((const float*)W_in)[i];
        if (t < HID)
            bs[t] = f ? b2f(((const bf16_t*)b_in)[t]) : ((const float*)b_in)[t];
        __syncthreads();
        int nb = bid - 463;
        int wid = t >> 6, c = t & 63;
#pragma unroll
        for (int g = 0; g < 8; g++) {
            int node = (nb * 8 + g) * 4 + wid;
            if (node >= NN) break;
            float acc = bs[c];
            if (f) {
                const bf16_t* fr = (const bf16_t*)feat_raw + (size_t)node * IN_DIM;
#pragma unroll
                for (int k = 0; k < IN_DIM; k++) acc += b2f(fr[k]) * Ws[k * HID + c];
            } else {
                const float* fr = (const float*)feat_raw + (size_t)node * IN_DIM;
#pragma unroll
                for (int k = 0; k < IN_DIM; k++) acc += fr[k] * Ws[k * HID + c];
            }
            bf16_t o = f2b(acc);
            h0[(size_t)node * HID + c] = o;
            h [(size_t)node * HID + c] = o;
        }
    }
}

// ---------------------------------------------------------------- hist: edge degree + mask buckets
__global__ __launch_bounds__(256) void k_hist_all(const int* __restrict__ dst,
                                                  const int* __restrict__ mask,
                                                  int* __restrict__ deg,
                                                  int* __restrict__ mbuf) {
    int t = threadIdx.x, bid = blockIdx.x;
    int i = bid * 256 + t;
    if (i < EE) atomicAdd(&deg[dst[i]], 1);
    if (bid < (NN + 255) / 256) {
        __shared__ int wcnt[4][4];
        int wid = t >> 6, lane = t & 63;
        int ni = bid * 256 + t;
        bool valid = ni < NN;
        int v = 0;
        if (valid) { int m = mask[ni]; v = m < 0 ? 0 : (m > 3 ? 3 : m); }
#pragma unroll
        for (int b = 0; b < 4; b++) {
            unsigned long long mm = __ballot(valid && v == b);
            if (lane == 0) wcnt[wid][b] = __popcll(mm);
        }
        __syncthreads();
        if (t < 4) {
            int s = wcnt[0][t] + wcnt[1][t] + wcnt[2][t] + wcnt[3][t];
            if (s) atomicAdd(&mbuf[t], s);
        }
    }
}

// ---------------------------------------------------------------- CSR scans
__global__ __launch_bounds__(256) void k_scan_partial(const int* __restrict__ deg,
                                                      int* __restrict__ part, int n) {
    __shared__ int sd[256];
    int t = threadIdx.x;
    int base = blockIdx.x * 1024;
    int s = 0;
#pragma unroll
    for (int j = 0; j < 4; j++) {
        int i = base + t * 4 + j;
        if (i < n) s += deg[i];
    }
    sd[t] = s; __syncthreads();
    for (int off = 128; off > 0; off >>= 1) {
        if (t < off) sd[t] += sd[t + off];
        __syncthreads();
    }
    if (t == 0) part[blockIdx.x] = sd[0];
}

// scan_final with merged chunk-prefix + mbuf offset computation
// mbuf: [0..3] counts, [4..7] cursors (bucket v at mbuf[4+v]), [8..10] active/step
__global__ __launch_bounds__(256) void k_scan_final(const int* __restrict__ deg,
                                                    const int* __restrict__ part,
                                                    int* __restrict__ row_ptr,
                                                    int* __restrict__ cursor,
                                                    int n, int nch,
                                                    int* __restrict__ mbuf) {
    __shared__ int sc[256];
    __shared__ int bpref;
    int t = threadIdx.x;
    int bid = blockIdx.x;
    if (t == 0) {
        int acc = 0;
        for (int i = 0; i < bid; i++) acc += part[i];
        bpref = acc;
        if (bid == 0) {
            int tot = 0;
            for (int i = 0; i < nch; i++) tot += part[i];
            row_ptr[n] = tot;
            int c1 = mbuf[1], c2 = mbuf[2], c3 = mbuf[3];
            mbuf[7] = 0;              // bucket 3 cursor
            mbuf[6] = c3;             // bucket 2
            mbuf[5] = c3 + c2;        // bucket 1
            mbuf[4] = c3 + c2 + c1;   // bucket 0
            mbuf[8] = c3 + c2 + c1;   // active at step 0
            mbuf[9] = c3 + c2;        // step 1
            mbuf[10] = c3;            // step 2
        }
    }
    int base = bid * 1024;
    int v[4]; int s = 0;
#pragma unroll
    for (int j = 0; j < 4; j++) {
        int i = base + t * 4 + j;
        v[j] = (i < n) ? deg[i] : 0;
        s += v[j];
    }
    sc[t] = s; __syncthreads();
    for (int off = 1; off < 256; off <<= 1) {
        int add = (t >= off) ? sc[t - off] : 0;
        __syncthreads();
        sc[t] += add;
        __syncthreads();
    }
    int run = sc[t] - s + bpref;
#pragma unroll
    for (int j = 0; j < 4; j++) {
        int i = base + t * 4 + j;
        if (i < n) { row_ptr[i] = run; cursor[i] = run; run += v[j]; }
    }
}

// ---------------------------------------------------------------- scatter: CSR cols (mask-packed) + compaction order
__global__ __launch_bounds__(256) void k_scatter_all(const int* __restrict__ src,
                                                     const int* __restrict__ dst,
                                                     int* __restrict__ cursor,
                                                     int* __restrict__ col,
                                                     const int* __restrict__ mask,
                                                     int* __restrict__ mbuf,
                                                     int* __restrict__ order) {
    int t = threadIdx.x, bid = blockIdx.x;
    int i = bid * 256 + t;
    if (i < EE) {
        int sv = src[i];
        int m = mask[sv]; m = m < 0 ? 0 : (m > 3 ? 3 : m);
        int d = dst[i];
        int pos = atomicAdd(&cursor[d], 1);   // 50k distinct addrs: fine
        col[pos] = sv | (m << 28);
    }
    if (bid < (NN + 255) / 256) {
        __shared__ int wcnt[4][4];
        __shared__ int bbase[4];
        int wid = t >> 6, lane = t & 63;
        int ni = bid * 256 + t;
        bool valid = ni < NN;
        int v = 0;
        if (valid) { int m = mask[ni]; v = m < 0 ? 0 : (m > 3 ? 3 : m); }
        int rank = 0;
#pragma unroll
        for (int b = 0; b < 4; b++) {
            unsigned long long mm = __ballot(valid && v == b);
            if (valid && v == b)
                rank = __popcll(mm & ((lane == 0) ? 0ull : (~0ull >> (64 - lane))));
            if (lane == 0) wcnt[wid][b] = __popcll(mm);
        }
        __syncthreads();
        if (t < 4) {
            int tot = wcnt[0][t] + wcnt[1][t] + wcnt[2][t] + wcnt[3][t];
            bbase[t] = atomicAdd(&mbuf[4 + t], tot);   // one atomic/bucket/block
        }
        __syncthreads();
        if (valid) {
            int wpre = 0;
            for (int ww = 0; ww < wid; ww++) wpre += wcnt[ww][v];
            order[bbase[v] + wpre + rank] = ni;
        }
    }
}

// ---------------------------------------------------------------- step-0 MFMA GEMM (K=64, pre-summed weights)
__global__ __launch_bounds__(256) void k_gemm0(const bf16_t* __restrict__ h0,
                                               const bf16_t* __restrict__ WtS,
                                               const float* __restrict__ bb,
                                               bf16_t* __restrict__ xl,
                                               bf16_t* __restrict__ xr,
                                               const int* __restrict__ order,
                                               const int* __restrict__ mbuf) {
    int count = mbuf[8];
    int mbase = blockIdx.x * 64;
    if (mbase >= count) return;

    __shared__ bf16_t smem[64 * 72 + 128 * 72];   // 27.6 KB
    bf16_t* As = smem;
    bf16_t* Bs = smem + 64 * 72;
    bf16_t* Cs = smem;                             // 64*136=8704 <= 13824

    int t = threadIdx.x;
    int nbase = blockIdx.y * 128;

    {
        int ln = t >> 2, lq = t & 3;
        int idx = mbase + ln;
        int node = (idx < count) ? order[idx] : -1;
        ulonglong2 z; z.x = 0; z.y = 0;
        ulonglong2 v0 = z, v1 = z;
        if (node >= 0) {
            v0 = *(const ulonglong2*)(h0 + (size_t)node * HID + lq * 16);
            v1 = *(const ulonglong2*)(h0 + (size_t)node * HID + lq * 16 + 8);
        }
        *(ulonglong2*)(&As[ln * 72 + lq * 16]) = v0;
        *(ulonglong2*)(&As[ln * 72 + lq * 16 + 8]) = v1;
    }
    {
        int n = t >> 1, kc = (t & 1) * 32;
        const bf16_t* srcp = WtS + (size_t)(nbase + n) * 64 + kc;
        bf16_t* dstp = &Bs[n * 72 + kc];
        *(ulonglong2*)(dstp)      = *(const ulonglong2*)(srcp);
        *(ulonglong2*)(dstp + 8)  = *(const ulonglong2*)(srcp + 8);
        *(ulonglong2*)(dstp + 16) = *(const ulonglong2*)(srcp + 16);
        *(ulonglong2*)(dstp + 24) = *(const ulonglong2*)(srcp + 24);
    }
    __syncthreads();

    int wv = t >> 6, lane = t & 63, mrow = lane & 15, quad = lane >> 4;
    floatx4 acc[8];
#pragma unroll
    for (int nf = 0; nf < 8; nf++) acc[nf] = (floatx4){0.f, 0.f, 0.f, 0.f};
#pragma unroll
    for (int kq = 0; kq < 2; kq++) {
        short8 a = *(const short8*)(&As[(wv * 16 + mrow) * 72 + kq * 32 + quad * 8]);
#pragma unroll
        for (int nf = 0; nf < 8; nf++) {
            short8 b = *(const short8*)(&Bs[(nf * 16 + mrow) * 72 + kq * 32 + quad * 8]);
            acc[nf] = __builtin_amdgcn_mfma_f32_16x16x32_bf16(a, b, acc[nf], 0, 0, 0);
        }
    }
    __syncthreads();

#pragma unroll
    for (int nf = 0; nf < 8; nf++) {
        float bv = bb[nbase + nf * 16 + mrow];
#pragma unroll
        for (int r = 0; r < 4; r++) {
            int m = wv * 16 + quad * 4 + r;
            Cs[m * 136 + nf * 16 + mrow] = f2b(acc[nf][r] + bv);
        }
    }
    __syncthreads();

    bf16_t* outp = (blockIdx.y < 2) ? xl : xr;
    int cc = (blockIdx.y & 1) * 128;
#pragma unroll
    for (int i = 0; i < 4; i++) {
        int c = t + i * 256;
        int m = c >> 4, kc = (c & 15) * 8;
        int idx = mbase + m;
        if (idx < count) {
            int node = order[idx];
            *(ulonglong2*)(outp + (size_t)node * 256 + cc + kc) =
                *(const ulonglong2*)(&Cs[m * 136 + kc]);
        }
    }
}

// ---------------------------------------------------------------- steps 1-2 MFMA GEMM (K=128)
__global__ __launch_bounds__(256) void k_gemm_mfma(const bf16_t* __restrict__ h,
                                                   const bf16_t* __restrict__ h0,
                                                   const bf16_t* __restrict__ Wt,
                                                   const float* __restrict__ bb,
                                                   bf16_t* __restrict__ xl,
                                                   bf16_t* __restrict__ xr,
                                                   const int* __restrict__ order,
                                                   const int* __restrict__ mbuf,
                                                   int step) {
    int count = mbuf[8 + step];
    int mbase = blockIdx.x * 64;
    if (mbase >= count) return;

    __shared__ bf16_t smem[64 * 136 + 128 * 136];   // 52 KB
    bf16_t* As = smem;
    bf16_t* Bs = smem + 64 * 136;
    bf16_t* Cs = smem;

    int t = threadIdx.x;
    int nbase = blockIdx.y * 128;

    {
        int ln = t >> 2, lq = t & 3;
        int idx = mbase + ln;
        int node = (idx < count) ? order[idx] : -1;
        ulonglong2 z; z.x = 0; z.y = 0;
#pragma unroll
        for (int j = 0; j < 2; j++) {
            int chunk = lq + j * 4;
            ulonglong2 vh = z, vh0 = z;
            if (node >= 0) {
                vh  = *(const ulonglong2*)(h  + (size_t)node * HID + chunk * 8);
                vh0 = *(const ulonglong2*)(h0 + (size_t)node * HID + chunk * 8);
            }
            *(ulonglong2*)(&As[ln * 136 + chunk * 8]) = vh;
            *(ulonglong2*)(&As[ln * 136 + 64 + chunk * 8]) = vh0;
        }
    }
#pragma unroll
    for (int i = 0; i < 8; i++) {
        int c = t + i * 256;
        int n = c >> 4, kc = (c & 15) * 8;
        *(ulonglong2*)(&Bs[n * 136 + kc]) =
            *(const ulonglong2*)(Wt + (size_t)(nbase + n) * 128 + kc);
    }
    __syncthreads();

    int wv = t >> 6, lane = t & 63, mrow = lane & 15, quad = lane >> 4;
    floatx4 acc[8];
#pragma unroll
    for (int nf = 0; nf < 8; nf++) acc[nf] = (floatx4){0.f, 0.f, 0.f, 0.f};
#pragma unroll
    for (int kq = 0; kq < 4; kq++) {
        short8 a = *(const short8*)(&As[(wv * 16 + mrow) * 136 + kq * 32 + quad * 8]);
#pragma unroll
        for (int nf = 0; nf < 8; nf++) {
            short8 b = *(const short8*)(&Bs[(nf * 16 + mrow) * 136 + kq * 32 + quad * 8]);
            acc[nf] = __builtin_amdgcn_mfma_f32_16x16x32_bf16(a, b, acc[nf], 0, 0, 0);
        }
    }
    __syncthreads();

#pragma unroll
    for (int nf = 0; nf < 8; nf++) {
        float bv = bb[nbase + nf * 16 + mrow];
#pragma unroll
        for (int r = 0; r < 4; r++) {
            int m = wv * 16 + quad * 4 + r;
            Cs[m * 136 + nf * 16 + mrow] = f2b(acc[nf][r] + bv);
        }
    }
    __syncthreads();

    bf16_t* outp = (blockIdx.y < 2) ? xl : xr;
    int cc = (blockIdx.y & 1) * 128;
#pragma unroll
    for (int i = 0; i < 4; i++) {
        int c = t + i * 256;
        int m = c >> 4, kc = (c & 15) * 8;
        int idx = mbase + m;
        if (idx < count) {
            int node = order[idx];
            *(ulonglong2*)(outp + (size_t)node * 256 + cc + kc) =
                *(const ulonglong2*)(&Cs[m * 136 + kc]);
        }
    }
}

// ---------------------------------------------------------------- segment softmax + aggregate (in-place bf16 h)
__global__ __launch_bounds__(256) void k_agg(bf16_t* __restrict__ h,
                                             const bf16_t* __restrict__ xl,
                                             const bf16_t* __restrict__ xr,
                                             const float* __restrict__ att,
                                             const float* __restrict__ b_conv,
                                             const int* __restrict__ row_ptr,
                                             const int* __restrict__ col,
                                             const int* __restrict__ order,
                                             const int* __restrict__ mbuf,
                                             int step) {
    int count = mbuf[8 + step];
    int wid = threadIdx.x >> 6;
    int lane = threadIdx.x & 63;
    float4 attv = *(const float4*)(att + lane * 4);
    float4 bcv  = *(const float4*)(b_conv + lane * 4);

    for (int idx = blockIdx.x * 4 + wid; idx < count; idx += gridDim.x * 4) {
        int node = order[idx];

        ushort4 xru = *(const ushort4*)(xr + (size_t)node * 256 + lane * 4);
        float xr0 = b2f(xru.x), xr1 = b2f(xru.y), xr2 = b2f(xru.z), xr3 = b2f(xru.w);

        float a0 = 0.f, a1 = 0.f, a2 = 0.f, a3 = 0.f, l = 0.f;

        auto do_edge = [&](int s) {
            ushort4 xu = *(const ushort4*)(xl + (size_t)s * 256 + lane * 4);
            float x0 = b2f(xu.x), x1 = b2f(xu.y), x2 = b2f(xu.z), x3 = b2f(xu.w);
            float v0 = x0 + xr0; v0 = v0 > 0.f ? v0 : 0.2f * v0;
            float v1 = x1 + xr1; v1 = v1 > 0.f ? v1 : 0.2f * v1;
            float v2 = x2 + xr2; v2 = v2 > 0.f ? v2 : 0.2f * v2;
            float v3 = x3 + xr3; v3 = v3 > 0.f ? v3 : 0.2f * v3;
            float part = attv.x * v0 + attv.y * v1 + attv.z * v2 + attv.w * v3;
            part += __shfl_xor(part, 1, 64);
            part += __shfl_xor(part, 2, 64);
            part += __shfl_xor(part, 4, 64);
            part += __shfl_xor(part, 8, 64);
            float p = __expf(part);
            l += p;
            a0 += p * x0; a1 += p * x1; a2 += p * x2; a3 += p * x3;
        };

        do_edge(node);                                    // implicit self-loop
        int e0 = row_ptr[node], e1 = row_ptr[node + 1];
        int e = e0;
        for (; e + 3 < e1; e += 4) {
            int c0 = col[e], c1 = col[e + 1], c2 = col[e + 2], c3 = col[e + 3];
            if (((unsigned)c0 >> 28) > (unsigned)step) do_edge(c0 & 0x0FFFFFFF);
            if (((unsigned)c1 >> 28) > (unsigned)step) do_edge(c1 & 0x0FFFFFFF);
            if (((unsigned)c2 >> 28) > (unsigned)step) do_edge(c2 & 0x0FFFFFFF);
            if (((unsigned)c3 >> 28) > (unsigned)step) do_edge(c3 & 0x0FFFFFFF);
        }
        for (; e < e1; e++) {
            int c = col[e];
            if (((unsigned)c >> 28) > (unsigned)step) do_edge(c & 0x0FFFFFFF);
        }

        float inv = 1.f / l;                              // l>0 (self-loop alive)
        float t0 = a0 * inv + bcv.x;
        float t1 = a1 * inv + bcv.y;
        float t2 = a2 * inv + bcv.z;
        float t3 = a3 * inv + bcv.w;
        t0 += __shfl_xor(t0, 16, 64); t0 += __shfl_xor(t0, 32, 64);
        t1 += __shfl_xor(t1, 16, 64); t1 += __shfl_xor(t1, 32, 64);
        t2 += __shfl_xor(t2, 16, 64); t2 += __shfl_xor(t2, 32, 64);
        t3 += __shfl_xor(t3, 16, 64); t3 += __shfl_xor(t3, 32, 64);
        if (lane < 16) {
            ushort4 o;
            o.x = f2b(tanhf(t0)); o.y = f2b(tanhf(t1));
            o.z = f2b(tanhf(t2)); o.w = f2b(tanhf(t3));
            *(ushort4*)(h + (size_t)node * HID + lane * 4) = o;
        }
    }
}

// ---------------------------------------------------------------- out = (h @ Wg + bg) * (cs>0)
__global__ __launch_bounds__(256) void k_out(const bf16_t* __restrict__ h,
                                             const float* __restrict__ Wg,
                                             const float* __restrict__ bg,
                                             const int* __restrict__ cs,
                                             void* __restrict__ out,
                                             const int* __restrict__ flag) {
    __shared__ float Ws[HID * OUTD];
    __shared__ float bs[OUTD];
    int t = threadIdx.x;
    for (int i = t; i < HID * OUTD; i += 256) Ws[i] = Wg[i];
    if (t < OUTD) bs[t] = bg[t];
    __syncthreads();
    int node = blockIdx.x * 8 + (t >> 5);
    int c = t & 31;
    if (node >= NN) return;
    float res = 0.f;
    if (cs[node] > 0) {
        const bf16_t* hr = h + (size_t)node * HID;
        float acc = bs[c];
#pragma unroll
        for (int k = 0; k < HID; k++) acc += b2f(hr[k]) * Ws[k * OUTD + c];
        res = acc;
    }
    size_t idx = (size_t)node * OUTD + c;
    if (*flag) ((bf16_t*)out)[idx] = f2b(res);
    else       ((float*)out)[idx]  = res;
}

// ---------------------------------------------------------------- host
static inline size_t alignup(size_t x) { return (x + 255) & ~(size_t)255; }

extern "C" void kernel_launch(void* const* d_in, const int* in_sizes, int n_in,
                              void* d_out, int out_size, void* d_ws, size_t ws_size,
                              hipStream_t stream) {
    const void* feat_raw  = d_in[0];
    const void* W_in_raw  = d_in[1];
    const void* b_in_raw  = d_in[2];
    const void* Wl_raw    = d_in[3];
    const void* bl_raw    = d_in[4];
    const void* Wr_raw    = d_in[5];
    const void* br_raw    = d_in[6];
    const void* att_raw   = d_in[7];
    const void* bconv_raw = d_in[8];
    const void* Wg_raw    = d_in[9];
    const void* bg_raw    = d_in[10];
    const int* edge       = (const int*)d_in[11];    // [2][EE]: src row, dst row
    const int* nmask      = (const int*)d_in[12];
    const int* cstate     = (const int*)d_in[13];

    const int* e_src = edge;
    const int* e_dst = edge + EE;

    const size_t SZ_HB   = alignup((size_t)NN * HID * sizeof(bf16_t));
    const size_t SZ_X    = alignup((size_t)NN * 256 * sizeof(bf16_t));
    const size_t SZ_I    = alignup((size_t)NN * sizeof(int));
    const size_t SZ_RP   = alignup((size_t)(NN + 1) * sizeof(int));
    const size_t SZ_COL  = alignup((size_t)EE * sizeof(int));
    const int nch = (NN + 1023) / 1024;
    const size_t SZ_PART = alignup((size_t)(nch + 1) * sizeof(int));
    const size_t SZ_WT   = alignup((size_t)512 * 128 * sizeof(bf16_t));
    const size_t SZ_WTS  = alignup((size_t)512 * 64 * sizeof(bf16_t));
    const size_t SZ_B    = alignup(512 * sizeof(float));
    const size_t SZ_WG   = alignup((size_t)HID * OUTD * sizeof(float));

    char* w = (char*)d_ws;
    bf16_t* h0   = (bf16_t*)w; w += SZ_HB;
    bf16_t* h    = (bf16_t*)w; w += SZ_HB;
    bf16_t* xl   = (bf16_t*)w; w += SZ_X;
    bf16_t* xr   = (bf16_t*)w; w += SZ_X;
    int* deg     = (int*)w;    w += SZ_I;
    int* row_ptr = (int*)w;    w += SZ_RP;
    int* cursor  = (int*)w;    w += SZ_I;
    int* colA    = (int*)w;    w += SZ_COL;
    int* order   = (int*)w;    w += SZ_I;
    int* part    = (int*)w;    w += SZ_PART;
    bf16_t* Wt   = (bf16_t*)w; w += SZ_WT;
    bf16_t* WtS  = (bf16_t*)w; w += SZ_WTS;
    float* bb    = (float*)w;  w += SZ_B;
    float* attf  = (float*)w;  w += SZ_B;
    float* bcf   = (float*)w;  w += SZ_B;
    float* Wgf   = (float*)w;  w += SZ_WG;
    float* bgf   = (float*)w;  w += SZ_B;
    int* flag    = (int*)w;    w += 256;
    int* mbuf    = (int*)w;    w += 256;
    if ((size_t)(w - (char*)d_ws) > ws_size) return;

    // ---- fused setup: flag + weights (Wt, WtS, bb, small) + deg/mbuf zero + h0
    k_setup<<<463 + H0_BLOCKS, 256, 0, stream>>>(
        W_in_raw, b_in_raw, att_raw, bconv_raw, Wg_raw, bg_raw,
        Wl_raw, Wr_raw, bl_raw, br_raw, feat_raw,
        attf, bcf, Wgf, bgf, Wt, WtS, bb, deg, flag, mbuf, h0, h);

    // ---- CSR + compaction
    k_hist_all<<<(EE + 255) / 256, 256, 0, stream>>>(e_dst, nmask, deg, mbuf);
    k_scan_partial<<<nch, 256, 0, stream>>>(deg, part, NN);
    k_scan_final<<<nch, 256, 0, stream>>>(deg, part, row_ptr, cursor, NN, nch, mbuf);
    k_scatter_all<<<(EE + 255) / 256, 256, 0, stream>>>(e_src, e_dst, cursor, colA,
                                                        nmask, mbuf, order);

    // ---- step 0: K=64 gemm with pre-summed weights (h==h0), then agg
    k_gemm0<<<dim3((NN + 63) / 64, 4), 256, 0, stream>>>(h0, WtS, bb, xl, xr, order, mbuf);
    k_agg<<<2048, 256, 0, stream>>>(h, xl, xr, attf, bcf, row_ptr, colA, order, mbuf, 0);

    // ---- steps 1,2: K=128 gemm + agg
    for (int s = 1; s < TSTEPS; s++) {
        k_gemm_mfma<<<dim3((NN + 63) / 64, 4), 256, 0, stream>>>(h, h0, Wt, bb, xl, xr,
                                                                 order, mbuf, s);
        k_agg<<<2048, 256, 0, stream>>>(h, xl, xr, attf, bcf,
                                        row_ptr, colA, order, mbuf, s);
    }

    // ---- epilogue
    k_out<<<(NN + 7) / 8, 256, 0, stream>>>(h, Wgf, bgf, cstate, d_out, flag);
}